// Round 1
// baseline (21869.699 us; speedup 1.0000x reference)
//
#include <hip/hip_runtime.h>
#include <hip/hip_bf16.h>

#define TLEN 65536
#define NSEQ 32
#define HID 8
#define MAXD 10000

// ---------------------------------------------------------------------------
// Kernel 1: GRU over time. 8 lanes per sequence (lane j owns hidden unit j),
// 8 sequences per wave, 4 waves total (one per block -> separate CUs).
// Writes pre_d = h_t . w_out directly into the second half of d_out.
// ---------------------------------------------------------------------------
__global__ __launch_bounds__(64, 1) void gru_kernel(
    const float* __restrict__ x,      // (NSEQ, TLEN)
    const float* __restrict__ w_ih,   // (24, 1)
    const float* __restrict__ w_hh,   // (24, 8) row-major
    const float* __restrict__ b_ih,   // (24,)
    const float* __restrict__ b_hh,   // (24,)
    const float* __restrict__ w_out,  // (1, 8)
    float* __restrict__ pre_d)        // (NSEQ, TLEN)
{
    const int lane = threadIdx.x;     // 0..63
    const int grp  = lane >> 3;       // sequence within wave
    const int j    = lane & 7;        // hidden unit index
    const int seq  = blockIdx.x * 8 + grp;

    // Per-lane weights: rows j (r), 8+j (z), 16+j (n) of w_hh.
    float whr[8], whz[8], whn[8];
#pragma unroll
    for (int k = 0; k < 8; ++k) {
        whr[k] = w_hh[(0 * 8 + j) * 8 + k];
        whz[k] = w_hh[(1 * 8 + j) * 8 + k];
        whn[k] = w_hh[(2 * 8 + j) * 8 + k];
    }
    const float wir = w_ih[j], wiz = w_ih[8 + j], win = w_ih[16 + j];
    const float br  = b_ih[j]      + b_hh[j];        // r-gate bias (combined)
    const float bz  = b_ih[8 + j]  + b_hh[8 + j];    // z-gate bias (combined)
    const float bin_ = b_ih[16 + j];                 // n-gate: b_ih outside r*
    const float bhn  = b_hh[16 + j];                 // n-gate: b_hh inside r*
    const float wo   = w_out[j];

    const float* xs = x     + (size_t)seq * TLEN;
    float*       pd = pre_d + (size_t)seq * TLEN;

    float h = 0.0f;

    for (int t = 0; t < TLEN; ++t) {
        const float xt = xs[t];                      // same addr across group
        // off-chain input projections
        const float gr = fmaf(xt, wir, br);
        const float gz = fmaf(xt, wiz, bz);
        const float gn = fmaf(xt, win, bin_);

        // gh = W_hh h + b_hh  (three 8-dots; h broadcast within 8-lane group)
        float ar = 0.0f, az = 0.0f, an = bhn;
#pragma unroll
        for (int k = 0; k < 8; ++k) {
            const float hk = __shfl(h, k, 8);
            ar = fmaf(whr[k], hk, ar);
            az = fmaf(whz[k], hk, az);
            an = fmaf(whn[k], hk, an);
        }

        const float r = 1.0f / (1.0f + __expf(-(gr + ar)));
        const float z = 1.0f / (1.0f + __expf(-(gz + az)));
        const float nv = fmaf(r, an, gn);
        // tanh(nv) = 1 - 2/(1+e^{2nv}); saturates correctly at +-inf
        const float e2 = __expf(2.0f * nv);
        const float n_ = 1.0f - 2.0f / (1.0f + e2);
        h = fmaf(z, h - n_, n_);                     // (1-z)*n + z*h

        // pre_d[t] = sum_j h[j]*w_out[j]  (off the recurrence critical path)
        float s = h * wo;
        s += __shfl_xor(s, 1, 8);
        s += __shfl_xor(s, 2, 8);
        s += __shfl_xor(s, 4, 8);
        if (j == 0) pd[t] = s;
    }
}

// ---------------------------------------------------------------------------
// Kernel 2: time-varying fractional delay (2-tap gather). Fully parallel.
// ---------------------------------------------------------------------------
__global__ void delay_kernel(
    const float* __restrict__ pre_d,  // (NSEQ, TLEN)
    const float* __restrict__ dt,     // (NSEQ, TLEN)
    const float* __restrict__ buffer, // (NSEQ, MAXD) -- zeros from setup
    float* __restrict__ y)            // (NSEQ, TLEN)
{
    const int idx = blockIdx.x * blockDim.x + threadIdx.x;
    if (idx >= NSEQ * TLEN) return;
    const int n = idx >> 16;          // TLEN == 2^16
    const int t = idx & (TLEN - 1);

    const float d  = dt[idx];
    const float p  = (float)MAXD - d;       // fractional tap position
    const float k0 = floorf(p);
    const float frac = p - k0;              // w1
    const float w0 = 1.0f - frac;

    const int k0i = (int)k0;
    const int k1i = min(k0i + 1, MAXD);
    const int i0 = t + k0i - MAXD;          // index into pre_d (may be <0)
    const int i1 = t + k1i - MAXD;

    const float* pdn  = pre_d  + (size_t)n * TLEN;
    const float* bufn = buffer + (size_t)n * MAXD;

    const float y0 = (i0 >= 0) ? pdn[i0] : bufn[t + k0i];
    const float y1 = (i1 >= 0) ? pdn[i1] : bufn[t + k1i];

    y[idx] = fmaf(w0, y0, frac * y1);
}

extern "C" void kernel_launch(void* const* d_in, const int* in_sizes, int n_in,
                              void* d_out, int out_size, void* d_ws, size_t ws_size,
                              hipStream_t stream) {
    const float* x      = (const float*)d_in[0];
    const float* dtraj  = (const float*)d_in[1];
    const float* buffer = (const float*)d_in[2];
    const float* w_ih   = (const float*)d_in[3];
    const float* w_hh   = (const float*)d_in[4];
    const float* b_ih   = (const float*)d_in[5];
    const float* b_hh   = (const float*)d_in[6];
    const float* w_out  = (const float*)d_in[7];

    float* y     = (float*)d_out;                    // output 0: (32,1,65536)
    float* pre_d = (float*)d_out + (size_t)NSEQ * TLEN; // output 1

    // GRU: 4 blocks x 64 threads (one wave each; 8 sequences per wave)
    gru_kernel<<<dim3(4), dim3(64), 0, stream>>>(x, w_ih, w_hh, b_ih, b_hh,
                                                 w_out, pre_d);

    // Delay line: one thread per (n, t)
    const int total = NSEQ * TLEN;
    delay_kernel<<<dim3((total + 255) / 256), dim3(256), 0, stream>>>(
        pre_d, dtraj, buffer, y);
}

// Round 2
// 10105.898 us; speedup vs baseline: 2.1641x; 2.1641x over previous
//
#include <hip/hip_runtime.h>
#include <hip/hip_bf16.h>

#define TLEN 65536
#define NSEQ 32
#define MAXD 10000

__device__ __forceinline__ float rl(float v, int l) {
    return __uint_as_float(__builtin_amdgcn_readlane(__float_as_uint(v), l));
}
__device__ __forceinline__ float rcp_(float x) { return __builtin_amdgcn_rcpf(x); }
__device__ __forceinline__ float ex2_(float x) { return __builtin_amdgcn_exp2f(x); }

// ---------------------------------------------------------------------------
// GRU: ONE sequence per wave (32 waves total). Lane j (= lane&7) owns hidden
// unit j; all 8-lane groups within the wave compute identical replicas (no
// divergence). h is broadcast via v_readlane -> SGPRs (VALU pipe, fast) —
// no ds_bpermute on the recurrence critical path. x is prefetched in
// double-buffered 16-step register chunks. Sigmoid/tanh use v_exp/v_rcp.
// pre_d[t-1] is computed from the SGPR broadcast of h_{t-1} at the top of
// step t (deferred by one step), stored from lane 0.
// ---------------------------------------------------------------------------
__global__ __launch_bounds__(64, 1) void gru_kernel(
    const float* __restrict__ x,      // (NSEQ, TLEN)
    const float* __restrict__ w_ih,   // (24, 1)
    const float* __restrict__ w_hh,   // (24, 8) row-major
    const float* __restrict__ b_ih,   // (24,)
    const float* __restrict__ b_hh,   // (24,)
    const float* __restrict__ w_out,  // (1, 8)
    float* __restrict__ pre_d)        // (NSEQ, TLEN)
{
    const int lane = threadIdx.x & 63;
    const int j    = lane & 7;
    const int seq  = blockIdx.x;

    float whr[8], whz[8], whn[8], wov[8];
#pragma unroll
    for (int k = 0; k < 8; ++k) {
        whr[k] = w_hh[(0  + j) * 8 + k];
        whz[k] = w_hh[(8  + j) * 8 + k];
        whn[k] = w_hh[(16 + j) * 8 + k];
        wov[k] = w_out[k];
    }
    const float wir = w_ih[j], wiz = w_ih[8 + j], win = w_ih[16 + j];
    const float br   = b_ih[j]      + b_hh[j];      // r bias (combined)
    const float bz   = b_ih[8 + j]  + b_hh[8 + j];  // z bias (combined)
    const float bn_i = b_ih[16 + j];                // n bias outside r*
    const float bn_h = b_hh[16 + j];                // n bias inside  r*

    const float*  xs  = x     + (size_t)seq * TLEN;
    float*        pd  = pre_d + (size_t)seq * TLEN;
    const float4* xs4 = (const float4*)xs;

    const float NL2E = -1.44269504088896f;   // -log2(e)
    const float PL2E =  2.88539008177793f;   // 2*log2(e)

    float h = 0.0f;

    const int NCH = TLEN / 16;
    float4 a0 = xs4[0], a1 = xs4[1], a2 = xs4[2], a3 = xs4[3];

    for (int c = 0; c < NCH; ++c) {
        // prefetch next chunk (clamped re-load of last chunk at the end)
        const int cn = (c + 1 < NCH) ? (c + 1) : c;
        float4 b0 = xs4[cn * 4 + 0], b1 = xs4[cn * 4 + 1];
        float4 b2 = xs4[cn * 4 + 2], b3 = xs4[cn * 4 + 3];

        float cx[16];
        cx[0]=a0.x; cx[1]=a0.y; cx[2]=a0.z; cx[3]=a0.w;
        cx[4]=a1.x; cx[5]=a1.y; cx[6]=a1.z; cx[7]=a1.w;
        cx[8]=a2.x; cx[9]=a2.y; cx[10]=a2.z; cx[11]=a2.w;
        cx[12]=a3.x; cx[13]=a3.y; cx[14]=a3.z; cx[15]=a3.w;

#pragma unroll
        for (int u = 0; u < 16; ++u) {
            // broadcast h_{t-1} to SGPRs (readlane: VALU pipe, no LDS)
            float hu[8];
#pragma unroll
            for (int k = 0; k < 8; ++k) hu[k] = rl(h, k);

            // gate pre-activations; matvec uses SGPR-broadcast h
            const float xt = cx[u];
            float ar = fmaf(xt, wir, br);
            float az = fmaf(xt, wiz, bz);
            const float gn = fmaf(xt, win, bn_i);
            float an = bn_h;
#pragma unroll
            for (int k = 0; k < 8; ++k) {
                ar = fmaf(whr[k], hu[k], ar);
                az = fmaf(whz[k], hu[k], az);
                an = fmaf(whn[k], hu[k], an);
            }

            // pre_d[t-1] = h_{t-1} . w_out  (off the recurrence chain)
            float s = hu[0] * wov[0];
#pragma unroll
            for (int k = 1; k < 8; ++k) s = fmaf(hu[k], wov[k], s);
            const int t = c * 16 + u;
            if (t > 0 && lane == 0) pd[t - 1] = s;

            // nonlinearity: sigmoid(x)=rcp(1+2^(-x*log2e)); tanh via 2^(2x*log2e)
            const float r = rcp_(1.0f + ex2_(ar * NL2E));
            const float z = rcp_(1.0f + ex2_(az * NL2E));
            const float nv = fmaf(r, an, gn);
            const float n_ = fmaf(-2.0f, rcp_(1.0f + ex2_(nv * PL2E)), 1.0f);
            h = fmaf(z, h - n_, n_);             // (1-z)*n + z*h
        }
        a0 = b0; a1 = b1; a2 = b2; a3 = b3;
    }

    // final pre_d[TLEN-1]
    {
        float hu[8];
#pragma unroll
        for (int k = 0; k < 8; ++k) hu[k] = rl(h, k);
        float s = hu[0] * wov[0];
#pragma unroll
        for (int k = 1; k < 8; ++k) s = fmaf(hu[k], wov[k], s);
        if (lane == 0) pd[TLEN - 1] = s;
    }
}

// ---------------------------------------------------------------------------
// Kernel 2: time-varying fractional delay (2-tap gather). Fully parallel.
// ---------------------------------------------------------------------------
__global__ void delay_kernel(
    const float* __restrict__ pre_d,  // (NSEQ, TLEN)
    const float* __restrict__ dt,     // (NSEQ, TLEN)
    const float* __restrict__ buffer, // (NSEQ, MAXD) -- zeros from setup
    float* __restrict__ y)            // (NSEQ, TLEN)
{
    const int idx = blockIdx.x * blockDim.x + threadIdx.x;
    if (idx >= NSEQ * TLEN) return;
    const int n = idx >> 16;          // TLEN == 2^16
    const int t = idx & (TLEN - 1);

    const float d  = dt[idx];
    const float p  = (float)MAXD - d;       // fractional tap position
    const float k0 = floorf(p);
    const float frac = p - k0;              // w1
    const float w0 = 1.0f - frac;

    const int k0i = (int)k0;
    const int k1i = min(k0i + 1, MAXD);
    const int i0 = t + k0i - MAXD;          // index into pre_d (may be <0)
    const int i1 = t + k1i - MAXD;

    const float* pdn  = pre_d  + (size_t)n * TLEN;
    const float* bufn = buffer + (size_t)n * MAXD;

    const float y0 = (i0 >= 0) ? pdn[i0] : bufn[t + k0i];
    const float y1 = (i1 >= 0) ? pdn[i1] : bufn[t + k1i];

    y[idx] = fmaf(w0, y0, frac * y1);
}

extern "C" void kernel_launch(void* const* d_in, const int* in_sizes, int n_in,
                              void* d_out, int out_size, void* d_ws, size_t ws_size,
                              hipStream_t stream) {
    const float* x      = (const float*)d_in[0];
    const float* dtraj  = (const float*)d_in[1];
    const float* buffer = (const float*)d_in[2];
    const float* w_ih   = (const float*)d_in[3];
    const float* w_hh   = (const float*)d_in[4];
    const float* b_ih   = (const float*)d_in[5];
    const float* b_hh   = (const float*)d_in[6];
    const float* w_out  = (const float*)d_in[7];

    float* y     = (float*)d_out;                       // output 0: (32,1,65536)
    float* pre_d = (float*)d_out + (size_t)NSEQ * TLEN; // output 1

    // GRU: one sequence per wave -> 32 blocks x 64 threads
    gru_kernel<<<dim3(NSEQ), dim3(64), 0, stream>>>(x, w_ih, w_hh, b_ih, b_hh,
                                                    w_out, pre_d);

    // Delay line: one thread per (n, t)
    const int total = NSEQ * TLEN;
    delay_kernel<<<dim3((total + 255) / 256), dim3(256), 0, stream>>>(
        pre_d, dtraj, buffer, y);
}